// Round 5
// baseline (3062.994 us; speedup 1.0000x reference)
//
#include <hip/hip_runtime.h>
#include <hip/hip_bf16.h>
#include <stdint.h>

#define NODES 50000
#define RELS  4
#define EDGES 1600000
#define FEAT  256
#define NCLS  16
#define MPAD  50048                 // 391 * 128
#define RPS   50016                 // row_ptr per-relation stride
#define SCHUNK 1024                 // scan elements per block
#define NSBLK  49                   // ceil(50000/1024)
#define NCHUNK 16                   // edge chunks per relation
#define CHUNKE 100000               // EDGES / NCHUNK
#define WIN    12500                // nodes per LDS window
#define NWIN   4                    // 4 * 12500 = 50000

typedef __attribute__((ext_vector_type(8))) short short8;
typedef __attribute__((ext_vector_type(8))) unsigned short u16x8;
typedef __attribute__((ext_vector_type(4))) float f32x4;

static __device__ __forceinline__ float bf2f(unsigned short u) {
    return __uint_as_float(((unsigned int)u) << 16);
}
static __device__ __forceinline__ unsigned short f2bf(float f) {
    unsigned int x = __float_as_uint(f);
    unsigned int r = x + 0x7fffu + ((x >> 16) & 1u);
    return (unsigned short)(r >> 16);
}

// ---------------- CSR build: atomic-free counting sort ----------------

// per-chunk LDS histogram -> plain partial writes. arr_off: 0 = rows, EDGES = cols
__global__ __launch_bounds__(256)
void k_histp(const int* __restrict__ edges, unsigned int* __restrict__ part, int arr_off) {
    int chunk = blockIdx.x, rel = blockIdx.y, t = threadIdx.x;
    const int* arr = edges + (size_t)rel * 2 * EDGES + arr_off + (size_t)chunk * CHUNKE;
    unsigned int* pout = part + ((size_t)rel * NCHUNK + chunk) * NODES;
    __shared__ unsigned int h[WIN];
    for (int w = 0; w < NWIN; ++w) {
        int lo = w * WIN;
        for (int i = t; i < WIN; i += 256) h[i] = 0;
        __syncthreads();
        for (int e = t; e < CHUNKE; e += 256) {
            unsigned int d = (unsigned int)(arr[e] - lo);
            if (d < WIN) atomicAdd(&h[d], 1u);
        }
        __syncthreads();
        for (int i = t; i < WIN; i += 256) pout[lo + i] = h[i];
        __syncthreads();
    }
}

// sum partials -> deg_row (for scan), dinv_row, dinv_col
__global__ void k_reduce(const unsigned int* __restrict__ phist,
                         const unsigned int* __restrict__ pcol,
                         int* __restrict__ deg_row,
                         float* __restrict__ dinv_row, float* __restrict__ dinv_col) {
    int idx = blockIdx.x * blockDim.x + threadIdx.x;
    if (idx >= RELS * NODES) return;
    int rel = idx / NODES, n = idx - rel * NODES;
    unsigned int sr = 0, sc = 0;
    for (int b = 0; b < NCHUNK; ++b) {
        sr += phist[((size_t)rel * NCHUNK + b) * NODES + n];
        sc += pcol[((size_t)rel * NCHUNK + b) * NODES + n];
    }
    deg_row[idx] = (int)sr;
    dinv_row[idx] = rsqrtf((float)(sr < 1u ? 1u : sr));
    dinv_col[idx] = rsqrtf((float)(sc < 1u ? 1u : sc));
}

// -------- parallel exclusive scan of deg_row -> row_ptr (3 kernels) --------
__global__ __launch_bounds__(256)
void k_scanA(const int* __restrict__ deg, int* __restrict__ tmp, int* __restrict__ btot) {
    int r = blockIdx.y, blk = blockIdx.x, t = threadIdx.x;
    int i0 = blk * SCHUNK + t * 4;
    const int* d = deg + (size_t)r * NODES;
    int4 v = make_int4(0, 0, 0, 0);
    if (i0 + 3 < NODES) v = *(const int4*)(d + i0);
    else if (i0 < NODES) {
        v.x = d[i0];
        if (i0 + 1 < NODES) v.y = d[i0 + 1];
        if (i0 + 2 < NODES) v.z = d[i0 + 2];
    }
    int s = v.x + v.y + v.z + v.w;
    __shared__ int sh[256];
    sh[t] = s;
    __syncthreads();
    for (int off = 1; off < 256; off <<= 1) {
        int u = (t >= off) ? sh[t - off] : 0;
        __syncthreads();
        sh[t] += u;
        __syncthreads();
    }
    int excl = sh[t] - s;
    int4 o;
    o.x = excl; o.y = excl + v.x; o.z = o.y + v.y; o.w = o.z + v.z;
    int* tp = tmp + (size_t)r * NODES;
    if (i0 + 3 < NODES) *(int4*)(tp + i0) = o;
    else if (i0 < NODES) {
        tp[i0] = o.x;
        if (i0 + 1 < NODES) tp[i0 + 1] = o.y;
        if (i0 + 2 < NODES) tp[i0 + 2] = o.z;
    }
    if (t == 255) btot[r * 64 + blk] = sh[255];
}

__global__ void k_scanB(int* __restrict__ btot, int* __restrict__ row_ptr) {
    int r = blockIdx.x;
    if (threadIdx.x != 0) return;
    int acc = 0;
    for (int b = 0; b < NSBLK; ++b) {
        int v = btot[r * 64 + b];
        btot[r * 64 + b] = acc;
        acc += v;
    }
    row_ptr[r * RPS + NODES] = acc;
}

__global__ __launch_bounds__(256)
void k_scanC(const int* __restrict__ tmp, const int* __restrict__ btot,
             int* __restrict__ row_ptr) {
    int r = blockIdx.y, blk = blockIdx.x, t = threadIdx.x;
    int i0 = blk * SCHUNK + t * 4;
    int off = btot[r * 64 + blk];
    const int* tp = tmp + (size_t)r * NODES;
    int* rp = row_ptr + (size_t)r * RPS;
    if (i0 + 3 < NODES) {
        int4 v = *(const int4*)(tp + i0);
        rp[i0] = v.x + off; rp[i0 + 1] = v.y + off;
        rp[i0 + 2] = v.z + off; rp[i0 + 3] = v.w + off;
    } else if (i0 < NODES) {
        for (int j = 0; j < 4 && i0 + j < NODES; ++j)
            rp[i0 + j] = tp[i0 + j] + off;
    }
}

// per-(chunk,row) slot base: boff[rel][b][n] = row_ptr[n] + sum_{b'<b} phist[rel][b'][n]
__global__ void k_boff(const unsigned int* __restrict__ phist, const int* __restrict__ row_ptr,
                       int* __restrict__ boff) {
    int idx = blockIdx.x * blockDim.x + threadIdx.x;
    if (idx >= RELS * NODES) return;
    int rel = idx / NODES, n = idx - rel * NODES;
    int acc = row_ptr[(size_t)rel * RPS + n];
    for (int b = 0; b < NCHUNK; ++b) {
        size_t o = ((size_t)rel * NCHUNK + b) * NODES + n;
        boff[o] = acc;
        acc += (int)phist[o];
    }
}

// scatter fill: LDS cursors seeded from boff; zero global atomics
__global__ __launch_bounds__(256)
void k_fills(const int* __restrict__ edges, const int* __restrict__ boff,
             int* __restrict__ csr_col) {
    int chunk = blockIdx.x, rel = blockIdx.y, t = threadIdx.x;
    const int* rows = edges + (size_t)rel * 2 * EDGES + (size_t)chunk * CHUNKE;
    const int* cols = rows + EDGES;
    const int* bo = boff + ((size_t)rel * NCHUNK + chunk) * NODES;
    int* cc = csr_col + (size_t)rel * EDGES;
    __shared__ int cur[WIN];
    for (int w = 0; w < NWIN; ++w) {
        int lo = w * WIN;
        for (int i = t; i < WIN; i += 256) cur[i] = bo[lo + i];
        __syncthreads();
        for (int e = t; e < CHUNKE; e += 256) {
            unsigned int d = (unsigned int)(rows[e] - lo);
            if (d < WIN) {
                int pos = atomicAdd(&cur[d], 1);
                cc[pos] = cols[e];
            }
        }
        __syncthreads();
    }
}

// ---------------- conversions ----------------

__global__ void k_f2bf(const float* __restrict__ src, unsigned short* __restrict__ dst, int count) {
    int i = blockIdx.x * blockDim.x + threadIdx.x;
    if (i < count) dst[i] = f2bf(src[i]);
}

__global__ void k_wt(const float* __restrict__ W, unsigned short* __restrict__ Wt) {
    int idx = blockIdx.x * blockDim.x + threadIdx.x;
    if (idx >= RELS * FEAT * FEAT) return;
    int r = idx >> 16;
    int rem = idx & 65535;
    int n = rem >> 8;
    int k = rem & 255;
    Wt[idx] = f2bf(W[(size_t)r * FEAT * FEAT + (size_t)k * FEAT + n]);
}

// ---------------- SPMM: wave per row, 2 edges/iter, 2x unrolled, bf16 out ----------------

__global__ __launch_bounds__(256)
void k_spmm(const unsigned short* __restrict__ feat, const int* __restrict__ row_ptr,
            const int* __restrict__ csr_col, const float* __restrict__ dinv_row,
            const float* __restrict__ dinv_col, unsigned short* __restrict__ aggbf, int rel) {
    int wave = (blockIdx.x * blockDim.x + threadIdx.x) >> 6;
    int lane = threadIdx.x & 63;
    if (wave >= NODES) return;
    int row = wave;
    int half = lane >> 5;
    int l32  = lane & 31;
    int start = row_ptr[rel * RPS + row];
    int end   = row_ptr[rel * RPS + row + 1];
    const int* cols = csr_col + (size_t)rel * EDGES;
    const float* dc = dinv_col + rel * NODES;
    const unsigned short* fb = feat + l32 * 8;
    float acc[8] = {0.f, 0.f, 0.f, 0.f, 0.f, 0.f, 0.f, 0.f};
    int j = start + half;
    for (; j + 2 < end; j += 4) {
        int c0 = cols[j];
        int c1 = cols[j + 2];
        float w0 = dc[c0];
        float w1 = dc[c1];
        u16x8 u0 = *(const u16x8*)(fb + (size_t)c0 * FEAT);
        u16x8 u1 = *(const u16x8*)(fb + (size_t)c1 * FEAT);
#pragma unroll
        for (int i = 0; i < 8; ++i) acc[i] += w0 * bf2f(u0[i]);
#pragma unroll
        for (int i = 0; i < 8; ++i) acc[i] += w1 * bf2f(u1[i]);
    }
    if (j < end) {
        int c0 = cols[j];
        float w0 = dc[c0];
        u16x8 u0 = *(const u16x8*)(fb + (size_t)c0 * FEAT);
#pragma unroll
        for (int i = 0; i < 8; ++i) acc[i] += w0 * bf2f(u0[i]);
    }
#pragma unroll
    for (int i = 0; i < 8; ++i) acc[i] += __shfl_down(acc[i], 32, 64);
    if (half == 0) {
        float dr = dinv_row[rel * NODES + row];
        u16x8 o;
#pragma unroll
        for (int i = 0; i < 8; ++i) o[i] = f2bf(acc[i] * dr);
        *(u16x8*)(aggbf + (size_t)row * FEAT + l32 * 8) = o;
    }
}

// ---------------- MFMA GEMM (128x128 tile, BK=64, XOR-swizzled LDS) ----------------
// C/D layout: col = lane&15, row = quad*4 + reg.

__global__ __launch_bounds__(256)
void k_gemm1(const unsigned short* __restrict__ Abase, const unsigned short* __restrict__ Wt,
             unsigned short* __restrict__ h1bf) {
    __shared__ __align__(16) unsigned short As[128 * 64];
    __shared__ __align__(16) unsigned short Bs[128 * 64];
    int tid = threadIdx.x;
    int wave = tid >> 6, lane = tid & 63;
    int quad = lane >> 4, l16 = lane & 15;
    int wm = (wave & 1) * 64, wn = (wave >> 1) * 64;
    int row0 = blockIdx.x * 128, n0 = blockIdx.y * 128;

    f32x4 hacc[4][4];
#pragma unroll
    for (int mi = 0; mi < 4; ++mi)
#pragma unroll
        for (int ni = 0; ni < 4; ++ni)
            hacc[mi][ni] = (f32x4){0.f, 0.f, 0.f, 0.f};

    for (int r = 0; r < RELS; ++r) {
        const unsigned short* A  = Abase + (size_t)r * MPAD * FEAT;
        const unsigned short* Bt = Wt + (size_t)r * FEAT * FEAT;
        f32x4 acc[4][4];
#pragma unroll
        for (int mi = 0; mi < 4; ++mi)
#pragma unroll
            for (int ni = 0; ni < 4; ++ni)
                acc[mi][ni] = (f32x4){0.f, 0.f, 0.f, 0.f};

        for (int k0 = 0; k0 < FEAT; k0 += 64) {
#pragma unroll
            for (int issue = 0; issue < 4; ++issue) {
                int flat = issue * 256 + tid;
                int row = flat >> 3;
                int gr = flat & 7;
                int sg = gr ^ (row & 7);
                *(uint4*)&As[flat * 8] = *(const uint4*)(A + (size_t)(row0 + row) * FEAT + k0 + sg * 8);
                *(uint4*)&Bs[flat * 8] = *(const uint4*)(Bt + (size_t)(n0 + row) * FEAT + k0 + sg * 8);
            }
            __syncthreads();
#pragma unroll
            for (int ks = 0; ks < 2; ++ks) {
                int g = ks * 4 + quad;
                short8 af[4], bfr[4];
#pragma unroll
                for (int mi = 0; mi < 4; ++mi) {
                    int m = wm + mi * 16 + l16;
                    af[mi] = *(const short8*)&As[m * 64 + ((g ^ (m & 7)) << 3)];
                }
#pragma unroll
                for (int ni = 0; ni < 4; ++ni) {
                    int n = wn + ni * 16 + l16;
                    bfr[ni] = *(const short8*)&Bs[n * 64 + ((g ^ (n & 7)) << 3)];
                }
#pragma unroll
                for (int mi = 0; mi < 4; ++mi)
#pragma unroll
                    for (int ni = 0; ni < 4; ++ni)
                        acc[mi][ni] = __builtin_amdgcn_mfma_f32_16x16x32_bf16(af[mi], bfr[ni], acc[mi][ni], 0, 0, 0);
            }
            __syncthreads();
        }
#pragma unroll
        for (int mi = 0; mi < 4; ++mi)
#pragma unroll
            for (int ni = 0; ni < 4; ++ni)
#pragma unroll
                for (int i = 0; i < 4; ++i) {
                    float v = acc[mi][ni][i];
                    hacc[mi][ni][i] += 0.25f * (v > 0.f ? v : 0.f);
                }
    }

#pragma unroll
    for (int mi = 0; mi < 4; ++mi)
#pragma unroll
        for (int ni = 0; ni < 4; ++ni) {
            int col = n0 + wn + ni * 16 + l16;
#pragma unroll
            for (int i = 0; i < 4; ++i) {
                int row = row0 + wm + mi * 16 + quad * 4 + i;
                if (row < NODES) h1bf[(size_t)row * FEAT + col] = f2bf(hacc[mi][ni][i]);
            }
        }
}

__global__ __launch_bounds__(256)
void k_gemm2(const unsigned short* __restrict__ A, const unsigned short* __restrict__ Bt,
             unsigned short* __restrict__ H2) {
    __shared__ __align__(16) unsigned short As[128 * 64];
    __shared__ __align__(16) unsigned short Bs[128 * 64];
    int tid = threadIdx.x;
    int wave = tid >> 6, lane = tid & 63;
    int quad = lane >> 4, l16 = lane & 15;
    int wm = (wave & 1) * 64, wn = (wave >> 1) * 64;
    int row0 = blockIdx.x * 128, n0 = blockIdx.y * 128;

    f32x4 acc[4][4];
#pragma unroll
    for (int mi = 0; mi < 4; ++mi)
#pragma unroll
        for (int ni = 0; ni < 4; ++ni)
            acc[mi][ni] = (f32x4){0.f, 0.f, 0.f, 0.f};

    for (int k0 = 0; k0 < FEAT; k0 += 64) {
#pragma unroll
        for (int issue = 0; issue < 4; ++issue) {
            int flat = issue * 256 + tid;
            int row = flat >> 3;
            int gr = flat & 7;
            int sg = gr ^ (row & 7);
            *(uint4*)&As[flat * 8] = *(const uint4*)(A + (size_t)(row0 + row) * FEAT + k0 + sg * 8);
            *(uint4*)&Bs[flat * 8] = *(const uint4*)(Bt + (size_t)(n0 + row) * FEAT + k0 + sg * 8);
        }
        __syncthreads();
#pragma unroll
        for (int ks = 0; ks < 2; ++ks) {
            int g = ks * 4 + quad;
            short8 af[4], bfr[4];
#pragma unroll
            for (int mi = 0; mi < 4; ++mi) {
                int m = wm + mi * 16 + l16;
                af[mi] = *(const short8*)&As[m * 64 + ((g ^ (m & 7)) << 3)];
            }
#pragma unroll
            for (int ni = 0; ni < 4; ++ni) {
                int n = wn + ni * 16 + l16;
                bfr[ni] = *(const short8*)&Bs[n * 64 + ((g ^ (n & 7)) << 3)];
            }
#pragma unroll
            for (int mi = 0; mi < 4; ++mi)
#pragma unroll
                for (int ni = 0; ni < 4; ++ni)
                    acc[mi][ni] = __builtin_amdgcn_mfma_f32_16x16x32_bf16(af[mi], bfr[ni], acc[mi][ni], 0, 0, 0);
        }
        __syncthreads();
    }

#pragma unroll
    for (int mi = 0; mi < 4; ++mi)
#pragma unroll
        for (int ni = 0; ni < 4; ++ni) {
            int col = n0 + wn + ni * 16 + l16;
#pragma unroll
            for (int i = 0; i < 4; ++i) {
                int row = row0 + wm + mi * 16 + quad * 4 + i;
                if (row < NODES) {
                    float v = acc[mi][ni][i];
                    H2[(size_t)row * FEAT + col] = f2bf(v > 0.f ? v : 0.f);
                }
            }
        }
}

// ---------------- attention scores + softmax (wave per node) ----------------

__global__ __launch_bounds__(256)
void k_scores(const unsigned short* __restrict__ H2bf, const float* __restrict__ att_q,
              const float* __restrict__ tau_p, float* __restrict__ alpha_out) {
    int wave = (blockIdx.x * blockDim.x + threadIdx.x) >> 6;
    int lane = threadIdx.x & 63;
    if (wave >= NODES) return;
    int n = wave;
    float4 q = *(const float4*)(att_q + lane * 4);
    float s[RELS];
#pragma unroll
    for (int r = 0; r < RELS; ++r) {
        ushort4 u = *(const ushort4*)(H2bf + ((size_t)r * NODES + n) * FEAT + lane * 4);
        s[r] = bf2f(u.x) * q.x + bf2f(u.y) * q.y + bf2f(u.z) * q.z + bf2f(u.w) * q.w;
    }
#pragma unroll
    for (int off = 32; off > 0; off >>= 1) {
#pragma unroll
        for (int r = 0; r < RELS; ++r) s[r] += __shfl_down(s[r], off, 64);
    }
    if (lane == 0) {
        float tau = tau_p[0];
        tau = fminf(fmaxf(tau, 0.5f), 5.0f);
        float it = 1.0f / tau;
        float m = fmaxf(fmaxf(s[0], s[1]), fmaxf(s[2], s[3]));
        float e0 = expf((s[0] - m) * it);
        float e1 = expf((s[1] - m) * it);
        float e2 = expf((s[2] - m) * it);
        float e3 = expf((s[3] - m) * it);
        float inv = 1.0f / (e0 + e1 + e2 + e3);
        float4 al = { e0 * inv, e1 * inv, e2 * inv, e3 * inv };
        *(float4*)(alpha_out + (size_t)n * 4) = al;
    }
}

// ---------------- fused h2-combine + output GEMM ----------------

__global__ __launch_bounds__(256)
void k_logits(const unsigned short* __restrict__ H2bf, const float* __restrict__ alpha,
              const float* __restrict__ W_out, const float* __restrict__ b_out,
              float* __restrict__ logits) {
    int gid = blockIdx.x * blockDim.x + threadIdx.x;
    if (gid >= NODES * NCLS) return;
    int n = gid >> 4;
    int c = gid & 15;
    float a0 = 0.25f + alpha[(size_t)n * 4 + 0];
    float a1 = 0.25f + alpha[(size_t)n * 4 + 1];
    float a2 = 0.25f + alpha[(size_t)n * 4 + 2];
    float a3 = 0.25f + alpha[(size_t)n * 4 + 3];
    const unsigned short* h0 = H2bf + (size_t)n * FEAT;
    const size_t rs = (size_t)NODES * FEAT;
    float acc = b_out[c];
#pragma unroll 4
    for (int h = 0; h < FEAT; ++h) {
        float h2 = a0 * bf2f(h0[h]) + a1 * bf2f(h0[h + rs]) +
                   a2 * bf2f(h0[h + 2 * rs]) + a3 * bf2f(h0[h + 3 * rs]);
        acc += h2 * W_out[h * NCLS + c];
    }
    logits[gid] = acc;
}

// ---------------- launcher ----------------

static inline int cdiv(int a, int b) { return (a + b - 1) / b; }

extern "C" void kernel_launch(void* const* d_in, const int* in_sizes, int n_in,
                              void* d_out, int out_size, void* d_ws, size_t ws_size,
                              hipStream_t stream) {
    const float* X     = (const float*)d_in[0];
    const int*   edges = (const int*)d_in[1];
    const float* W1    = (const float*)d_in[2];
    const float* W2    = (const float*)d_in[3];
    const float* att_q = (const float*)d_in[4];
    const float* tau   = (const float*)d_in[5];
    const float* W_out = (const float*)d_in[6];
    const float* b_out = (const float*)d_in[7];

    float* logits = (float*)d_out;
    float* alpha  = logits + (size_t)NODES * NCLS;

    char* p = (char*)d_ws;
    auto carve = [&](size_t bytes) -> char* {
        char* q = p;
        p += (bytes + 255) & ~(size_t)255;
        return q;
    };
    int*   deg_row  = (int*)carve((size_t)RELS * NODES * 4);
    float* dinv_row = (float*)carve((size_t)RELS * NODES * 4);
    float* dinv_col = (float*)carve((size_t)RELS * NODES * 4);
    int*   row_ptr  = (int*)carve((size_t)RELS * RPS * 4 + 256);
    int*   tmp      = (int*)carve((size_t)RELS * NODES * 4);
    int*   btot     = (int*)carve((size_t)RELS * 64 * 4);
    int*   csr_col  = (int*)carve((size_t)RELS * EDGES * 4);
    unsigned short* Xbf  = (unsigned short*)carve((size_t)NODES * FEAT * 2);
    unsigned short* h1bf = (unsigned short*)carve((size_t)NODES * FEAT * 2);
    unsigned short* W1t  = (unsigned short*)carve((size_t)RELS * FEAT * FEAT * 2);
    unsigned short* W2t  = (unsigned short*)carve((size_t)RELS * FEAT * FEAT * 2);
    // BIG region, phase-aliased:
    //   CSR phase: phist / pcol / boff (38.4 MB, consumed before SPMM)
    //   layer 1:   agg[r] = BIG + r*AGGS (4 slices)
    //   layer 2:   agg0 = BIG, H2bf = BIG + AGGS
    const size_t AGGS = (size_t)MPAD * FEAT * 2;
    const size_t PART = (size_t)RELS * NCHUNK * NODES * 4;   // 12.8 MB
    char* BIG = carve(AGGS + (size_t)RELS * NODES * FEAT * 2);
    unsigned int* phist = (unsigned int*)BIG;
    unsigned int* pcol  = (unsigned int*)(BIG + PART);
    int*          boff  = (int*)(BIG + 2 * PART);
    unsigned short* aggbf = (unsigned short*)BIG;
    unsigned short* H2bf  = (unsigned short*)(BIG + AGGS);

    // CSR build (no global atomics anywhere)
    {
        dim3 hg(NCHUNK, RELS);
        k_histp<<<hg, 256, 0, stream>>>(edges, phist, 0);
        k_histp<<<hg, 256, 0, stream>>>(edges, pcol, EDGES);
        k_reduce<<<cdiv(RELS * NODES, 256), 256, 0, stream>>>(phist, pcol, deg_row,
                                                              dinv_row, dinv_col);
        dim3 sg(NSBLK, RELS);
        k_scanA<<<sg, 256, 0, stream>>>(deg_row, tmp, btot);
        k_scanB<<<RELS, 64, 0, stream>>>(btot, row_ptr);
        k_scanC<<<sg, 256, 0, stream>>>(tmp, btot, row_ptr);
        k_boff<<<cdiv(RELS * NODES, 256), 256, 0, stream>>>(phist, row_ptr, boff);
        k_fills<<<hg, 256, 0, stream>>>(edges, boff, csr_col);
    }

    // conversions
    k_f2bf<<<cdiv(NODES * FEAT, 256), 256, 0, stream>>>(X, Xbf, NODES * FEAT);
    k_wt<<<cdiv(RELS * FEAT * FEAT, 256), 256, 0, stream>>>(W1, W1t);
    k_wt<<<cdiv(RELS * FEAT * FEAT, 256), 256, 0, stream>>>(W2, W2t);

    dim3 gemm_grid(MPAD / 128, FEAT / 128);

    // Layer 1: 4 SPMMs into 4 agg slices, then one fused GEMM -> h1bf
    for (int r = 0; r < RELS; ++r)
        k_spmm<<<cdiv(NODES * 64, 256), 256, 0, stream>>>(Xbf, row_ptr, csr_col,
                                                          dinv_row, dinv_col,
                                                          aggbf + (size_t)r * MPAD * FEAT, r);
    k_gemm1<<<gemm_grid, 256, 0, stream>>>(aggbf, W1t, h1bf);

    // Layer 2: per relation, SPMM into slice 0 then GEMM -> H2bf[r]
    for (int r = 0; r < RELS; ++r) {
        k_spmm<<<cdiv(NODES * 64, 256), 256, 0, stream>>>(h1bf, row_ptr, csr_col,
                                                          dinv_row, dinv_col, aggbf, r);
        k_gemm2<<<gemm_grid, 256, 0, stream>>>(aggbf, W2t + (size_t)r * FEAT * FEAT,
                                               H2bf + (size_t)r * NODES * FEAT);
    }

    // attention + output
    k_scores<<<cdiv(NODES * 64, 256), 256, 0, stream>>>(H2bf, att_q, tau, alpha);
    k_logits<<<cdiv(NODES * NCLS, 256), 256, 0, stream>>>(H2bf, alpha, W_out, b_out, logits);
}

// Round 7
// 1630.523 us; speedup vs baseline: 1.8785x; 1.8785x over previous
//
#include <hip/hip_runtime.h>
#include <hip/hip_bf16.h>
#include <stdint.h>

#define NODES 50000
#define RELS  4
#define EDGES 1600000
#define FEAT  256
#define NCLS  16
#define MPAD  50048                 // 391 * 128
#define RPS   50016                 // row_ptr per-relation stride
#define SCHUNK 1024                 // scan elements per block
#define NSBLK  49                   // ceil(50000/1024)
#define NCHUNK 64                   // edge chunks per relation
#define CHUNKE 25000                // EDGES / NCHUNK
#define NB     782                  // node buckets of 64 rows (781*64+16)

typedef __attribute__((ext_vector_type(8))) short short8;
typedef __attribute__((ext_vector_type(8))) unsigned short u16x8;
typedef __attribute__((ext_vector_type(4))) float f32x4;

static __device__ __forceinline__ float bf2f(unsigned short u) {
    return __uint_as_float(((unsigned int)u) << 16);
}
static __device__ __forceinline__ unsigned short f2bf(float f) {
    unsigned int x = __float_as_uint(f);
    unsigned int r = x + 0x7fffu + ((x >> 16) & 1u);
    return (unsigned short)(r >> 16);
}

// ============ CSR build: bucket radix sort, zero global atomics ============

// per-(rel,chunk) LDS histogram of value>>6 -> part[rel][chunk][NB]
__global__ __launch_bounds__(256)
void k_bhist(const int* __restrict__ edges, int arr_off, unsigned* __restrict__ part) {
    int chunk = blockIdx.x, rel = blockIdx.y, t = threadIdx.x;
    const int* arr = edges + (size_t)rel * 2 * EDGES + arr_off + (size_t)chunk * CHUNKE;
    __shared__ unsigned h[NB];
    for (int i = t; i < NB; i += 256) h[i] = 0;
    __syncthreads();
    for (int e = t; e < CHUNKE; e += 256) atomicAdd(&h[((unsigned)arr[e]) >> 6], 1u);
    __syncthreads();
    unsigned* po = part + ((size_t)rel * NCHUNK + chunk) * NB;
    for (int i = t; i < NB; i += 256) po[i] = h[i];
}

// per relation: bucket bases (exclusive scan of totals) + per-(chunk,bucket) offsets
__global__ __launch_bounds__(256)
void k_bscan(const unsigned* __restrict__ part, unsigned* __restrict__ off,
             unsigned* __restrict__ bbase) {
    int rel = blockIdx.x, t = threadIdx.x;
    const int BPT = 4;                       // 256*4 >= NB
    int b0 = t * BPT;
    unsigned s = 0;
#pragma unroll
    for (int j = 0; j < BPT; ++j) {
        int b = b0 + j;
        unsigned x = 0;
        if (b < NB)
            for (int c = 0; c < NCHUNK; ++c)
                x += part[((size_t)rel * NCHUNK + c) * NB + b];
        s += x;
    }
    __shared__ unsigned sh[256];
    sh[t] = s;
    __syncthreads();
    for (int o = 1; o < 256; o <<= 1) {
        unsigned u = (t >= o) ? sh[t - o] : 0;
        __syncthreads();
        sh[t] += u;
        __syncthreads();
    }
    unsigned base = sh[t] - s;
#pragma unroll
    for (int j = 0; j < BPT; ++j) {
        int b = b0 + j;
        if (b < NB) {
            bbase[rel * (NB + 1) + b] = base;
            unsigned acc = base;
            for (int c = 0; c < NCHUNK; ++c) {
                size_t o2 = ((size_t)rel * NCHUNK + c) * NB + b;
                off[o2] = acc;
                acc += part[o2];
            }
            base = acc;
        }
    }
    if (t == 255) bbase[rel * (NB + 1) + NB] = sh[255];
}

// scatter (row,col) pairs into row-bucket order (LDS cursors, sequential-ish writes)
__global__ __launch_bounds__(256)
void k_scatR(const int* __restrict__ edges, const unsigned* __restrict__ off,
             int2* __restrict__ ebuf) {
    int chunk = blockIdx.x, rel = blockIdx.y, t = threadIdx.x;
    const int* rows = edges + (size_t)rel * 2 * EDGES + (size_t)chunk * CHUNKE;
    const int* cols = rows + EDGES;
    __shared__ unsigned cur[NB];
    const unsigned* po = off + ((size_t)rel * NCHUNK + chunk) * NB;
    for (int i = t; i < NB; i += 256) cur[i] = po[i];
    __syncthreads();
    int2* eb = ebuf + (size_t)rel * EDGES;
    for (int e = t; e < CHUNKE; e += 256) {
        int r = rows[e], c = cols[e];
        unsigned pos = atomicAdd(&cur[((unsigned)r) >> 6], 1u);
        eb[pos] = make_int2(r, c);
    }
}

// scatter col values into col-bucket order (for col-degree counting)
__global__ __launch_bounds__(256)
void k_scatC(const int* __restrict__ edges, const unsigned* __restrict__ off,
             int* __restrict__ cbuf) {
    int chunk = blockIdx.x, rel = blockIdx.y, t = threadIdx.x;
    const int* cols = edges + (size_t)rel * 2 * EDGES + EDGES + (size_t)chunk * CHUNKE;
    __shared__ unsigned cur[NB];
    const unsigned* po = off + ((size_t)rel * NCHUNK + chunk) * NB;
    for (int i = t; i < NB; i += 256) cur[i] = po[i];
    __syncthreads();
    int* cb = cbuf + (size_t)rel * EDGES;
    for (int e = t; e < CHUNKE; e += 256) {
        int c = cols[e];
        unsigned pos = atomicAdd(&cur[((unsigned)c) >> 6], 1u);
        cb[pos] = c;
    }
}

// per-bucket row counts -> deg_row
__global__ __launch_bounds__(256)
void k_countR(const int2* __restrict__ ebuf, const unsigned* __restrict__ bbase,
              int* __restrict__ deg_row) {
    int b = blockIdx.x, rel = blockIdx.y, t = threadIdx.x;
    unsigned s = bbase[rel * (NB + 1) + b], e = bbase[rel * (NB + 1) + b + 1];
    __shared__ unsigned cnt[64];
    if (t < 64) cnt[t] = 0;
    __syncthreads();
    const int2* eb = ebuf + (size_t)rel * EDGES;
    for (unsigned i = s + t; i < e; i += 256) atomicAdd(&cnt[eb[i].x & 63], 1u);
    __syncthreads();
    int base = b * 64;
    if (t < 64 && base + t < NODES) deg_row[(size_t)rel * NODES + base + t] = (int)cnt[t];
}

// per-bucket col counts -> deg_col
__global__ __launch_bounds__(256)
void k_countC(const int* __restrict__ cbuf, const unsigned* __restrict__ bbase,
              int* __restrict__ deg_col) {
    int b = blockIdx.x, rel = blockIdx.y, t = threadIdx.x;
    unsigned s = bbase[rel * (NB + 1) + b], e = bbase[rel * (NB + 1) + b + 1];
    __shared__ unsigned cnt[64];
    if (t < 64) cnt[t] = 0;
    __syncthreads();
    const int* cb = cbuf + (size_t)rel * EDGES;
    for (unsigned i = s + t; i < e; i += 256) atomicAdd(&cnt[cb[i] & 63], 1u);
    __syncthreads();
    int base = b * 64;
    if (t < 64 && base + t < NODES) deg_col[(size_t)rel * NODES + base + t] = (int)cnt[t];
}

__global__ void k_dinv(const int* __restrict__ deg_row, const int* __restrict__ deg_col,
                       float* dinv_row, float* dinv_col) {
    int idx = blockIdx.x * blockDim.x + threadIdx.x;
    if (idx >= RELS * NODES) return;
    int dr = deg_row[idx]; if (dr < 1) dr = 1;
    int dc = deg_col[idx]; if (dc < 1) dc = 1;
    dinv_row[idx] = rsqrtf((float)dr);
    dinv_col[idx] = rsqrtf((float)dc);
}

// -------- parallel exclusive scan of deg_row -> row_ptr --------
__global__ __launch_bounds__(256)
void k_scanA(const int* __restrict__ deg, int* __restrict__ tmp, int* __restrict__ btot) {
    int r = blockIdx.y, blk = blockIdx.x, t = threadIdx.x;
    int i0 = blk * SCHUNK + t * 4;
    const int* d = deg + (size_t)r * NODES;
    int4 v = make_int4(0, 0, 0, 0);
    if (i0 + 3 < NODES) v = *(const int4*)(d + i0);
    else if (i0 < NODES) {
        v.x = d[i0];
        if (i0 + 1 < NODES) v.y = d[i0 + 1];
        if (i0 + 2 < NODES) v.z = d[i0 + 2];
    }
    int s = v.x + v.y + v.z + v.w;
    __shared__ int sh[256];
    sh[t] = s;
    __syncthreads();
    for (int off = 1; off < 256; off <<= 1) {
        int u = (t >= off) ? sh[t - off] : 0;
        __syncthreads();
        sh[t] += u;
        __syncthreads();
    }
    int excl = sh[t] - s;
    int4 o;
    o.x = excl; o.y = excl + v.x; o.z = o.y + v.y; o.w = o.z + v.z;
    int* tp = tmp + (size_t)r * NODES;
    if (i0 + 3 < NODES) *(int4*)(tp + i0) = o;
    else if (i0 < NODES) {
        tp[i0] = o.x;
        if (i0 + 1 < NODES) tp[i0 + 1] = o.y;
        if (i0 + 2 < NODES) tp[i0 + 2] = o.z;
    }
    if (t == 255) btot[r * 64 + blk] = sh[255];
}

__global__ void k_scanB(int* __restrict__ btot, int* __restrict__ row_ptr) {
    int r = blockIdx.x;
    if (threadIdx.x != 0) return;
    int acc = 0;
    for (int b = 0; b < NSBLK; ++b) {
        int v = btot[r * 64 + b];
        btot[r * 64 + b] = acc;
        acc += v;
    }
    row_ptr[r * RPS + NODES] = acc;
}

__global__ __launch_bounds__(256)
void k_scanC(const int* __restrict__ tmp, const int* __restrict__ btot,
             int* __restrict__ row_ptr) {
    int r = blockIdx.y, blk = blockIdx.x, t = threadIdx.x;
    int i0 = blk * SCHUNK + t * 4;
    int off = btot[r * 64 + blk];
    const int* tp = tmp + (size_t)r * NODES;
    int* rp = row_ptr + (size_t)r * RPS;
    if (i0 + 3 < NODES) {
        int4 v = *(const int4*)(tp + i0);
        rp[i0] = v.x + off; rp[i0 + 1] = v.y + off;
        rp[i0 + 2] = v.z + off; rp[i0 + 3] = v.w + off;
    } else if (i0 < NODES) {
        for (int j = 0; j < 4 && i0 + j < NODES; ++j)
            rp[i0 + j] = tp[i0 + j] + off;
    }
}

// per-bucket exact CSR fill: 64 LDS cursors, bucket csr range is contiguous (~8 KB)
__global__ __launch_bounds__(256)
void k_place(const int2* __restrict__ ebuf, const unsigned* __restrict__ bbase,
             const int* __restrict__ row_ptr, int* __restrict__ csr_col) {
    int b = blockIdx.x, rel = blockIdx.y, t = threadIdx.x;
    unsigned s = bbase[rel * (NB + 1) + b], e = bbase[rel * (NB + 1) + b + 1];
    __shared__ int cur[64];
    int base = b * 64;
    const int* rp = row_ptr + (size_t)rel * RPS;
    if (t < 64) cur[t] = (base + t < NODES) ? rp[base + t] : 0;
    __syncthreads();
    const int2* eb = ebuf + (size_t)rel * EDGES;
    int* cc = csr_col + (size_t)rel * EDGES;
    for (unsigned i = s + t; i < e; i += 256) {
        int2 ec = eb[i];
        int pos = atomicAdd(&cur[ec.x - base], 1);
        cc[pos] = ec.y;
    }
}

// ---------------- conversions ----------------

__global__ void k_f2bf(const float* __restrict__ src, unsigned short* __restrict__ dst, int count) {
    int i = blockIdx.x * blockDim.x + threadIdx.x;
    if (i < count) dst[i] = f2bf(src[i]);
}

__global__ void k_wt(const float* __restrict__ W, unsigned short* __restrict__ Wt) {
    int idx = blockIdx.x * blockDim.x + threadIdx.x;
    if (idx >= RELS * FEAT * FEAT) return;
    int r = idx >> 16;
    int rem = idx & 65535;
    int n = rem >> 8;
    int k = rem & 255;
    Wt[idx] = f2bf(W[(size_t)r * FEAT * FEAT + (size_t)k * FEAT + n]);
}

// ---------------- SPMM: wave per row, 2 edges/iter, 2x unrolled, bf16 out ----------------

__global__ __launch_bounds__(256)
void k_spmm(const unsigned short* __restrict__ feat, const int* __restrict__ row_ptr,
            const int* __restrict__ csr_col, const float* __restrict__ dinv_row,
            const float* __restrict__ dinv_col, unsigned short* __restrict__ aggbf, int rel) {
    int wave = (blockIdx.x * blockDim.x + threadIdx.x) >> 6;
    int lane = threadIdx.x & 63;
    if (wave >= NODES) return;
    int row = wave;
    int half = lane >> 5;
    int l32  = lane & 31;
    int start = row_ptr[rel * RPS + row];
    int end   = row_ptr[rel * RPS + row + 1];
    const int* cols = csr_col + (size_t)rel * EDGES;
    const float* dc = dinv_col + rel * NODES;
    const unsigned short* fb = feat + l32 * 8;
    float acc[8] = {0.f, 0.f, 0.f, 0.f, 0.f, 0.f, 0.f, 0.f};
    int j = start + half;
    for (; j + 2 < end; j += 4) {
        int c0 = cols[j];
        int c1 = cols[j + 2];
        float w0 = dc[c0];
        float w1 = dc[c1];
        u16x8 u0 = *(const u16x8*)(fb + (size_t)c0 * FEAT);
        u16x8 u1 = *(const u16x8*)(fb + (size_t)c1 * FEAT);
#pragma unroll
        for (int i = 0; i < 8; ++i) acc[i] += w0 * bf2f(u0[i]);
#pragma unroll
        for (int i = 0; i < 8; ++i) acc[i] += w1 * bf2f(u1[i]);
    }
    if (j < end) {
        int c0 = cols[j];
        float w0 = dc[c0];
        u16x8 u0 = *(const u16x8*)(fb + (size_t)c0 * FEAT);
#pragma unroll
        for (int i = 0; i < 8; ++i) acc[i] += w0 * bf2f(u0[i]);
    }
#pragma unroll
    for (int i = 0; i < 8; ++i) acc[i] += __shfl_down(acc[i], 32, 64);
    if (half == 0) {
        float dr = dinv_row[rel * NODES + row];
        u16x8 o;
#pragma unroll
        for (int i = 0; i < 8; ++i) o[i] = f2bf(acc[i] * dr);
        *(u16x8*)(aggbf + (size_t)row * FEAT + l32 * 8) = o;
    }
}

// ---------------- MFMA GEMM (128x128 tile, BK=64, XOR-swizzled LDS) ----------------
// C/D layout: col = lane&15, row = quad*4 + reg.

__global__ __launch_bounds__(256)
void k_gemm1(const unsigned short* __restrict__ Abase, const unsigned short* __restrict__ Wt,
             unsigned short* __restrict__ h1bf) {
    __shared__ __align__(16) unsigned short As[128 * 64];
    __shared__ __align__(16) unsigned short Bs[128 * 64];
    int tid = threadIdx.x;
    int wave = tid >> 6, lane = tid & 63;
    int quad = lane >> 4, l16 = lane & 15;
    int wm = (wave & 1) * 64, wn = (wave >> 1) * 64;
    int row0 = blockIdx.x * 128, n0 = blockIdx.y * 128;

    f32x4 hacc[4][4];
#pragma unroll
    for (int mi = 0; mi < 4; ++mi)
#pragma unroll
        for (int ni = 0; ni < 4; ++ni)
            hacc[mi][ni] = (f32x4){0.f, 0.f, 0.f, 0.f};

    for (int r = 0; r < RELS; ++r) {
        const unsigned short* A  = Abase + (size_t)r * MPAD * FEAT;
        const unsigned short* Bt = Wt + (size_t)r * FEAT * FEAT;
        f32x4 acc[4][4];
#pragma unroll
        for (int mi = 0; mi < 4; ++mi)
#pragma unroll
            for (int ni = 0; ni < 4; ++ni)
                acc[mi][ni] = (f32x4){0.f, 0.f, 0.f, 0.f};

        for (int k0 = 0; k0 < FEAT; k0 += 64) {
#pragma unroll
            for (int issue = 0; issue < 4; ++issue) {
                int flat = issue * 256 + tid;
                int row = flat >> 3;
                int gr = flat & 7;
                int sg = gr ^ (row & 7);
                *(uint4*)&As[flat * 8] = *(const uint4*)(A + (size_t)(row0 + row) * FEAT + k0 + sg * 8);
                *(uint4*)&Bs[flat * 8] = *(const uint4*)(Bt + (size_t)(n0 + row) * FEAT + k0 + sg * 8);
            }
            __syncthreads();
#pragma unroll
            for (int ks = 0; ks < 2; ++ks) {
                int g = ks * 4 + quad;
                short8 af[4], bfr[4];
#pragma unroll
                for (int mi = 0; mi < 4; ++mi) {
                    int m = wm + mi * 16 + l16;
                    af[mi] = *(const short8*)&As[m * 64 + ((g ^ (m & 7)) << 3)];
                }
#pragma unroll
                for (int ni = 0; ni < 4; ++ni) {
                    int n = wn + ni * 16 + l16;
                    bfr[ni] = *(const short8*)&Bs[n * 64 + ((g ^ (n & 7)) << 3)];
                }
#pragma unroll
                for (int mi = 0; mi < 4; ++mi)
#pragma unroll
                    for (int ni = 0; ni < 4; ++ni)
                        acc[mi][ni] = __builtin_amdgcn_mfma_f32_16x16x32_bf16(af[mi], bfr[ni], acc[mi][ni], 0, 0, 0);
            }
            __syncthreads();
        }
#pragma unroll
        for (int mi = 0; mi < 4; ++mi)
#pragma unroll
            for (int ni = 0; ni < 4; ++ni)
#pragma unroll
                for (int i = 0; i < 4; ++i) {
                    float v = acc[mi][ni][i];
                    hacc[mi][ni][i] += 0.25f * (v > 0.f ? v : 0.f);
                }
    }

#pragma unroll
    for (int mi = 0; mi < 4; ++mi)
#pragma unroll
        for (int ni = 0; ni < 4; ++ni) {
            int col = n0 + wn + ni * 16 + l16;
#pragma unroll
            for (int i = 0; i < 4; ++i) {
                int row = row0 + wm + mi * 16 + quad * 4 + i;
                if (row < NODES) h1bf[(size_t)row * FEAT + col] = f2bf(hacc[mi][ni][i]);
            }
        }
}

__global__ __launch_bounds__(256)
void k_gemm2(const unsigned short* __restrict__ A, const unsigned short* __restrict__ Bt,
             unsigned short* __restrict__ H2) {
    __shared__ __align__(16) unsigned short As[128 * 64];
    __shared__ __align__(16) unsigned short Bs[128 * 64];
    int tid = threadIdx.x;
    int wave = tid >> 6, lane = tid & 63;
    int quad = lane >> 4, l16 = lane & 15;
    int wm = (wave & 1) * 64, wn = (wave >> 1) * 64;
    int row0 = blockIdx.x * 128, n0 = blockIdx.y * 128;

    f32x4 acc[4][4];
#pragma unroll
    for (int mi = 0; mi < 4; ++mi)
#pragma unroll
        for (int ni = 0; ni < 4; ++ni)
            acc[mi][ni] = (f32x4){0.f, 0.f, 0.f, 0.f};

    for (int k0 = 0; k0 < FEAT; k0 += 64) {
#pragma unroll
        for (int issue = 0; issue < 4; ++issue) {
            int flat = issue * 256 + tid;
            int row = flat >> 3;
            int gr = flat & 7;
            int sg = gr ^ (row & 7);
            *(uint4*)&As[flat * 8] = *(const uint4*)(A + (size_t)(row0 + row) * FEAT + k0 + sg * 8);
            *(uint4*)&Bs[flat * 8] = *(const uint4*)(Bt + (size_t)(n0 + row) * FEAT + k0 + sg * 8);
        }
        __syncthreads();
#pragma unroll
        for (int ks = 0; ks < 2; ++ks) {
            int g = ks * 4 + quad;
            short8 af[4], bfr[4];
#pragma unroll
            for (int mi = 0; mi < 4; ++mi) {
                int m = wm + mi * 16 + l16;
                af[mi] = *(const short8*)&As[m * 64 + ((g ^ (m & 7)) << 3)];
            }
#pragma unroll
            for (int ni = 0; ni < 4; ++ni) {
                int n = wn + ni * 16 + l16;
                bfr[ni] = *(const short8*)&Bs[n * 64 + ((g ^ (n & 7)) << 3)];
            }
#pragma unroll
            for (int mi = 0; mi < 4; ++mi)
#pragma unroll
                for (int ni = 0; ni < 4; ++ni)
                    acc[mi][ni] = __builtin_amdgcn_mfma_f32_16x16x32_bf16(af[mi], bfr[ni], acc[mi][ni], 0, 0, 0);
        }
        __syncthreads();
    }

#pragma unroll
    for (int mi = 0; mi < 4; ++mi)
#pragma unroll
        for (int ni = 0; ni < 4; ++ni) {
            int col = n0 + wn + ni * 16 + l16;
#pragma unroll
            for (int i = 0; i < 4; ++i) {
                int row = row0 + wm + mi * 16 + quad * 4 + i;
                if (row < NODES) {
                    float v = acc[mi][ni][i];
                    H2[(size_t)row * FEAT + col] = f2bf(v > 0.f ? v : 0.f);
                }
            }
        }
}

// ---------------- attention scores + softmax (wave per node) ----------------

__global__ __launch_bounds__(256)
void k_scores(const unsigned short* __restrict__ H2bf, const float* __restrict__ att_q,
              const float* __restrict__ tau_p, float* __restrict__ alpha_out) {
    int wave = (blockIdx.x * blockDim.x + threadIdx.x) >> 6;
    int lane = threadIdx.x & 63;
    if (wave >= NODES) return;
    int n = wave;
    float4 q = *(const float4*)(att_q + lane * 4);
    float s[RELS];
#pragma unroll
    for (int r = 0; r < RELS; ++r) {
        ushort4 u = *(const ushort4*)(H2bf + ((size_t)r * NODES + n) * FEAT + lane * 4);
        s[r] = bf2f(u.x) * q.x + bf2f(u.y) * q.y + bf2f(u.z) * q.z + bf2f(u.w) * q.w;
    }
#pragma unroll
    for (int off = 32; off > 0; off >>= 1) {
#pragma unroll
        for (int r = 0; r < RELS; ++r) s[r] += __shfl_down(s[r], off, 64);
    }
    if (lane == 0) {
        float tau = tau_p[0];
        tau = fminf(fmaxf(tau, 0.5f), 5.0f);
        float it = 1.0f / tau;
        float m = fmaxf(fmaxf(s[0], s[1]), fmaxf(s[2], s[3]));
        float e0 = expf((s[0] - m) * it);
        float e1 = expf((s[1] - m) * it);
        float e2 = expf((s[2] - m) * it);
        float e3 = expf((s[3] - m) * it);
        float inv = 1.0f / (e0 + e1 + e2 + e3);
        float4 al = { e0 * inv, e1 * inv, e2 * inv, e3 * inv };
        *(float4*)(alpha_out + (size_t)n * 4) = al;
    }
}

// ---------------- fused h2-combine + output GEMM ----------------

__global__ __launch_bounds__(256)
void k_logits(const unsigned short* __restrict__ H2bf, const float* __restrict__ alpha,
              const float* __restrict__ W_out, const float* __restrict__ b_out,
              float* __restrict__ logits) {
    int gid = blockIdx.x * blockDim.x + threadIdx.x;
    if (gid >= NODES * NCLS) return;
    int n = gid >> 4;
    int c = gid & 15;
    float a0 = 0.25f + alpha[(size_t)n * 4 + 0];
    float a1 = 0.25f + alpha[(size_t)n * 4 + 1];
    float a2 = 0.25f + alpha[(size_t)n * 4 + 2];
    float a3 = 0.25f + alpha[(size_t)n * 4 + 3];
    const unsigned short* h0 = H2bf + (size_t)n * FEAT;
    const size_t rs = (size_t)NODES * FEAT;
    float acc = b_out[c];
#pragma unroll 4
    for (int h = 0; h < FEAT; ++h) {
        float h2 = a0 * bf2f(h0[h]) + a1 * bf2f(h0[h + rs]) +
                   a2 * bf2f(h0[h + 2 * rs]) + a3 * bf2f(h0[h + 3 * rs]);
        acc += h2 * W_out[h * NCLS + c];
    }
    logits[gid] = acc;
}

// ---------------- launcher ----------------

static inline int cdiv(int a, int b) { return (a + b - 1) / b; }

extern "C" void kernel_launch(void* const* d_in, const int* in_sizes, int n_in,
                              void* d_out, int out_size, void* d_ws, size_t ws_size,
                              hipStream_t stream) {
    const float* X     = (const float*)d_in[0];
    const int*   edges = (const int*)d_in[1];
    const float* W1    = (const float*)d_in[2];
    const float* W2    = (const float*)d_in[3];
    const float* att_q = (const float*)d_in[4];
    const float* tau   = (const float*)d_in[5];
    const float* W_out = (const float*)d_in[6];
    const float* b_out = (const float*)d_in[7];

    float* logits = (float*)d_out;
    float* alpha  = logits + (size_t)NODES * NCLS;

    char* p = (char*)d_ws;
    auto carve = [&](size_t bytes) -> char* {
        char* q = p;
        p += (bytes + 255) & ~(size_t)255;
        return q;
    };
    int*   deg_row  = (int*)carve((size_t)RELS * NODES * 4);
    int*   deg_col  = (int*)carve((size_t)RELS * NODES * 4);
    float* dinv_row = (float*)carve((size_t)RELS * NODES * 4);
    float* dinv_col = (float*)carve((size_t)RELS * NODES * 4);
    int*   row_ptr  = (int*)carve((size_t)RELS * RPS * 4 + 256);
    int*   tmp      = (int*)carve((size_t)RELS * NODES * 4);
    int*   btot     = (int*)carve((size_t)RELS * 64 * 4);
    int*   csr_col  = (int*)carve((size_t)RELS * EDGES * 4);
    unsigned short* Xbf  = (unsigned short*)carve((size_t)NODES * FEAT * 2);
    unsigned short* h1bf = (unsigned short*)carve((size_t)NODES * FEAT * 2);
    unsigned short* W1t  = (unsigned short*)carve((size_t)RELS * FEAT * FEAT * 2);
    unsigned short* W2t  = (unsigned short*)carve((size_t)RELS * FEAT * FEAT * 2);
    // BIG region, phase-aliased:
    //   CSR phase:  ebuf(51.2M) | cbuf(25.6M) | partR/offR/partC/offC(~3.2M) | bbR/bbC
    //   layer 1:    agg[r] = BIG + r*AGGS (4 slices)
    //   layer 2:    agg0 = BIG, H2bf = BIG + AGGS
    const size_t AGGS = (size_t)MPAD * FEAT * 2;
    char* BIG = carve(AGGS + (size_t)RELS * NODES * FEAT * 2);
    int2*     ebuf = (int2*)BIG;
    int*      cbuf = (int*)(BIG + (size_t)RELS * EDGES * 8);
    char*     q = BIG + (size_t)RELS * EDGES * 12;
    unsigned* partR = (unsigned*)q;               q += (size_t)RELS * NCHUNK * NB * 4;
    unsigned* offR  = (unsigned*)q;               q += (size_t)RELS * NCHUNK * NB * 4;
    unsigned* partC = (unsigned*)q;               q += (size_t)RELS * NCHUNK * NB * 4;
    unsigned* offC  = (unsigned*)q;               q += (size_t)RELS * NCHUNK * NB * 4;
    unsigned* bbR   = (unsigned*)q;               q += (size_t)RELS * (NB + 1) * 4;
    unsigned* bbC   = (unsigned*)q;
    unsigned short* aggbf = (unsigned short*)BIG;
    unsigned short* H2bf  = (unsigned short*)(BIG + AGGS);

    // CSR build: bucket radix sort (zero global atomics, no memsets)
    {
        dim3 hg(NCHUNK, RELS);
        dim3 bg(NB, RELS);
        k_bhist<<<hg, 256, 0, stream>>>(edges, 0, partR);
        k_bhist<<<hg, 256, 0, stream>>>(edges, EDGES, partC);
        k_bscan<<<RELS, 256, 0, stream>>>(partR, offR, bbR);
        k_bscan<<<RELS, 256, 0, stream>>>(partC, offC, bbC);
        k_scatR<<<hg, 256, 0, stream>>>(edges, offR, ebuf);
        k_scatC<<<hg, 256, 0, stream>>>(edges, offC, cbuf);
        k_countR<<<bg, 256, 0, stream>>>(ebuf, bbR, deg_row);
        k_countC<<<bg, 256, 0, stream>>>(cbuf, bbC, deg_col);
        k_dinv<<<cdiv(RELS * NODES, 256), 256, 0, stream>>>(deg_row, deg_col, dinv_row, dinv_col);
        dim3 sg(NSBLK, RELS);
        k_scanA<<<sg, 256, 0, stream>>>(deg_row, tmp, btot);
        k_scanB<<<RELS, 64, 0, stream>>>(btot, row_ptr);
        k_scanC<<<sg, 256, 0, stream>>>(tmp, btot, row_ptr);
        k_place<<<bg, 256, 0, stream>>>(ebuf, bbR, row_ptr, csr_col);
    }

    // conversions
    k_f2bf<<<cdiv(NODES * FEAT, 256), 256, 0, stream>>>(X, Xbf, NODES * FEAT);
    k_wt<<<cdiv(RELS * FEAT * FEAT, 256), 256, 0, stream>>>(W1, W1t);
    k_wt<<<cdiv(RELS * FEAT * FEAT, 256), 256, 0, stream>>>(W2, W2t);

    dim3 gemm_grid(MPAD / 128, FEAT / 128);

    // Layer 1: 4 SPMMs into 4 agg slices, then one fused GEMM -> h1bf
    for (int r = 0; r < RELS; ++r)
        k_spmm<<<cdiv(NODES * 64, 256), 256, 0, stream>>>(Xbf, row_ptr, csr_col,
                                                          dinv_row, dinv_col,
                                                          aggbf + (size_t)r * MPAD * FEAT, r);
    k_gemm1<<<gemm_grid, 256, 0, stream>>>(aggbf, W1t, h1bf);

    // Layer 2: per relation, SPMM into slice 0 then GEMM -> H2bf[r]
    for (int r = 0; r < RELS; ++r) {
        k_spmm<<<cdiv(NODES * 64, 256), 256, 0, stream>>>(h1bf, row_ptr, csr_col,
                                                          dinv_row, dinv_col, aggbf, r);
        k_gemm2<<<gemm_grid, 256, 0, stream>>>(aggbf, W2t + (size_t)r * FEAT * FEAT,
                                               H2bf + (size_t)r * NODES * FEAT);
    }

    // attention + output
    k_scores<<<cdiv(NODES * 64, 256), 256, 0, stream>>>(H2bf, att_q, tau, alpha);
    k_logits<<<cdiv(NODES * NCLS, 256), 256, 0, stream>>>(H2bf, alpha, W_out, b_out, logits);
}